// Round 11
// baseline (292.904 us; speedup 1.0000x reference)
//
#include <hip/hip_runtime.h>
#include <stdint.h>

#define D_DIM 1024
#define T_DIM 4096
#define B_DIM 4
#define M_DIM 16384
#define NX 16777216UL
#define NW 1048576UL
#define NTOT 19922944UL
#define LOG8F 2.0794415416798357f
#define CHUNK_L 64
#define NCHUNK 64
#define WARM 16
#define NT2 16

typedef __attribute__((ext_vector_type(4))) float f32x4;
typedef __attribute__((ext_vector_type(8))) short bf16x8;

__device__ __forceinline__ unsigned short f2bf(float f) {
    unsigned u = __float_as_uint(f);
    u += 0x7fffu + ((u >> 16) & 1u);
    return (unsigned short)(u >> 16);
}
__device__ __forceinline__ unsigned packbf2(float x, float y) {
    unsigned ux = __float_as_uint(x);
    ux = (ux + 0x7fffu + ((ux >> 16) & 1u)) >> 16;
    unsigned uy = __float_as_uint(y);
    uy = (uy + 0x7fffu + ((uy >> 16) & 1u)) & 0xffff0000u;
    return ux | uy;
}
__device__ __forceinline__ float bfu(unsigned short p) {
    return __uint_as_float((unsigned)p << 16);
}
__device__ __forceinline__ float sigm(float x) { return 1.0f / (1.0f + __expf(-x)); }

__device__ __forceinline__ void gl_lds16(const void* g, void* l) {
    __builtin_amdgcn_global_load_lds(
        (const __attribute__((address_space(1))) void*)g,
        (__attribute__((address_space(3))) void*)l, 16, 0, 0);
}

// ---------------------------------------------------------------------------
// Kernel 0: convert x, W_r, W_i, W_x  fp32 -> bf16 (R10 grid-stride form).
// ---------------------------------------------------------------------------
__global__ __launch_bounds__(256) void cvt_kernel(
    const float* __restrict__ x, const float* __restrict__ Wr,
    const float* __restrict__ Wi, const float* __restrict__ Wx,
    unsigned short* __restrict__ xb, unsigned short* __restrict__ wb)
{
    const size_t stride = (size_t)gridDim.x * 256 * 8;
    for (size_t i = ((size_t)blockIdx.x * 256 + threadIdx.x) * 8;
         i < NTOT; i += stride) {
        const float* src;
        unsigned short* dst;
        size_t off;
        if (i < NX) {
            src = x; dst = xb; off = i;
        } else {
            size_t j = i - NX;
            size_t w = j >> 20;           // / NW
            off = j & (NW - 1);
            src = (w == 0) ? Wr : (w == 1 ? Wi : Wx);
            dst = wb + w * NW;
        }
        float4 v0 = *(const float4*)(src + off);
        float4 v1 = *(const float4*)(src + off + 4);
        uint4 o;
        o.x = packbf2(v0.x, v0.y);
        o.y = packbf2(v0.z, v0.w);
        o.z = packbf2(v1.x, v1.y);
        o.w = packbf2(v1.z, v1.w);
        *(uint4*)(dst + off) = o;
    }
}

// ---------------------------------------------------------------------------
// Kernel 1: 3-fused GEMM + gating. R11: BK=64, 2-deep ping-pong -- HALF the
//   barrier convoys of the R5/R9 body (which sat at 143.6 us / MfmaUtil 31%
//   across three schedule variants). Diagnosis: 1 block/CU (128 KB LDS), so
//   every barrier is a full 8-wave convoy; per 32-K tile the convoy +
//   LDS-read burst cost ~2680 cy vs 931 cy MFMA floor. Same LDS bytes,
//   same MFMA count, 16 barriers instead of 32.
//   - per tile: 8 gl_lds (issued right after the barrier; waited a full
//     tile (~4000 cy) later, so vmcnt(0) at the top is a free drain),
//     20 ds_read_b128, 48 MFMA (K=64 = 2 k-halves accumulated).
//   - race audit: stage(T+1) writes buf[(T+1)&1], not read in STEP(T);
//     it overwrites the buffer read in STEP(T-1), whose ds_reads each wave
//     drained (compiler lgkmcnt before its MFMAs) before the intervening
//     barrier. gl_lds visibility: own-wave vmcnt(0) precedes the barrier.
//   - 8-group XOR swizzle (cg ^= row&7): slot (r,c) holds global group
//     c^(r&7); reader asks G^(r&7) -> G. 16-lane column reads: 8 distinct
//     groups, 2 lanes/bank = free. gl_lds dest stays wave-linear.
//   - regs ~215 (acc 96 + frags 80 + offsets/addr) under the 256 cap of
//     (512,2) -- no spill (R4's trap was demand 320).
//   - bid&7 = d-tile = XCD keeps per-XCD W-slice L2-resident (proven).
//   - R8 proved B direct-to-reg 1.9x worse; R4 proved bigger tiles spill.
//   Epilogue (unchanged): gating + wtail chunk-tail copy for fused scan.
// ---------------------------------------------------------------------------
__global__ __launch_bounds__(512, 2) void fused_gemm(
    const unsigned short* __restrict__ xb, const unsigned short* __restrict__ wb,
    const float* __restrict__ b_r, const float* __restrict__ b_i,
    unsigned short* __restrict__ a_out, float* __restrict__ u_out,
    float* __restrict__ wtail)
{
    // per buffer (32768 ush = 64 KB): A[128][64] then B[3][128][64]
    __shared__ __align__(16) unsigned short lds[2][32768];   // 128 KB

    const int tid  = threadIdx.x;
    const int lane = tid & 63;
    const int wave = tid >> 6;
    const int wm = wave & 1;            // m-half (64 rows of 128)
    const int wn = wave >> 1;           // d-quarter (32 cols of 128)
    const int m0 = ((int)blockIdx.x >> 3) * 128;
    const int d0 = ((int)blockIdx.x & 7) * 128;
    const int frow = lane & 15;
    const int kgrp = lane >> 4;

    // staging: round g covers rows g*64 + tid/8, col-group tid&7 (of 8).
    // global source col-group inverse-swizzled: cgs = c ^ (row&7).
    // (row+64)&7 == row&7, so one source base serves both rounds (+64*D).
    const int r_0 = tid >> 3;           // 0..63
    const int c_0 = tid & 7;
    const int cgs = c_0 ^ (r_0 & 7);
    const unsigned short* srcA = xb + (size_t)(m0 + r_0) * D_DIM + cgs * 8;
    const unsigned short* srcB = wb + (size_t)(d0 + r_0) * D_DIM + cgs * 8;

    // reader offsets (ushort units), swizzle folded in; ks = K-half (0,1)
    int offA[4][2], offB[3][2][2];
    #pragma unroll
    for (int i = 0; i < 4; i++) {
        const int row = wm * 64 + i * 16 + frow;
        #pragma unroll
        for (int ks = 0; ks < 2; ks++)
            offA[i][ks] = row * 64 + ((((ks * 4) + kgrp) ^ (row & 7)) << 3);
    }
    #pragma unroll
    for (int w = 0; w < 3; w++)
        #pragma unroll
        for (int j = 0; j < 2; j++) {
            const int row = wn * 32 + j * 16 + frow;
            #pragma unroll
            for (int ks = 0; ks < 2; ks++)
                offB[w][j][ks] = 8192 + w * 8192 + row * 64 +
                                 ((((ks * 4) + kgrp) ^ (row & 7)) << 3);
        }

    f32x4 acc[3][4][2];
    #pragma unroll
    for (int w = 0; w < 3; w++)
        #pragma unroll
        for (int i = 0; i < 4; i++)
            #pragma unroll
            for (int j = 0; j < 2; j++) acc[w][i][j] = (f32x4){0.f, 0.f, 0.f, 0.f};

    auto stage = [&](int t) {           // 8 gl_lds per thread per 64-K tile
        unsigned short* L = &lds[t & 1][0];
        const int k0 = t << 6;
        gl_lds16(srcA + k0,                &L[tid * 8]);
        gl_lds16(srcA + 64 * D_DIM + k0,   &L[4096 + tid * 8]);
        #pragma unroll
        for (int w = 0; w < 3; w++) {
            const unsigned short* bw = srcB + (size_t)w * NW + k0;
            gl_lds16(bw,                &L[8192 + w * 8192 + tid * 8]);
            gl_lds16(bw + 64 * D_DIM,   &L[8192 + w * 8192 + 4096 + tid * 8]);
        }
    };

    stage(0);

    for (int t = 0; t < NT2; ++t) {
        // own stage(t) was issued a full tile ago -> this drain is free;
        // it also makes our gl_lds writes visible before the barrier.
        asm volatile("s_waitcnt vmcnt(0)" ::: "memory");
        __builtin_amdgcn_s_barrier();
        asm volatile("" ::: "memory");
        if (t + 1 < NT2) stage(t + 1);

        const unsigned short* Lb = &lds[t & 1][0];
        bf16x8 af[4][2], bf[3][2][2];
        #pragma unroll
        for (int i = 0; i < 4; i++)
            #pragma unroll
            for (int ks = 0; ks < 2; ks++)
                af[i][ks] = *(const bf16x8*)&Lb[offA[i][ks]];
        #pragma unroll
        for (int w = 0; w < 3; w++)
            #pragma unroll
            for (int j = 0; j < 2; j++)
                #pragma unroll
                for (int ks = 0; ks < 2; ks++)
                    bf[w][j][ks] = *(const bf16x8*)&Lb[offB[w][j][ks]];

        __builtin_amdgcn_s_setprio(1);
        #pragma unroll
        for (int ks = 0; ks < 2; ks++)
            #pragma unroll
            for (int w = 0; w < 3; w++)
                #pragma unroll
                for (int i = 0; i < 4; i++)
                    #pragma unroll
                    for (int j = 0; j < 2; j++)
                        acc[w][i][j] = __builtin_amdgcn_mfma_f32_16x16x32_bf16(
                            af[i][ks], bf[w][j][ks], acc[w][i][j], 0, 0, 0);
        __builtin_amdgcn_s_setprio(0);
    }

    // Epilogue. C/D layout: col(d) = lane&15, row(m) = (lane>>4)*4 + r.
    const int mb = m0 + wm * 64 + kgrp * 4;
    const int db = d0 + wn * 32 + frow;
    #pragma unroll
    for (int j = 0; j < 2; j++) {
        const int d = db + j * 16;
        const float br = b_r[d];
        const float bi = b_i[d];
        #pragma unroll
        for (int i = 0; i < 4; i++) {
            const int m = mb + i * 16;
            #pragma unroll
            for (int r = 0; r < 4; r++) {
                const int mr = m + r;
                const size_t idx = (size_t)mr * D_DIM + d;
                float rg = sigm(acc[0][i][j][r] + br);
                // exp(-softplus(z)) == sigmoid(-z);  a in (0.11, 0.5)
                float a = sigm(-LOG8F * rg);
                a_out[idx] = f2bf(a);
                float g = sqrtf(fmaxf(1.0f - a * a, 1e-6f));
                float uval = g * sigm(acc[1][i][j][r] + bi) * acc[2][i][j][r];
                u_out[idx] = uval;
                // chunk-tail copy for the fused scan's warm-up.
                // (mr&63)>=48 <=> i==3 here (kgrp*4+r <= 15).
                if (i == 3) {
                    const int t = mr & 4095;
                    if (t < 4032) {     // c_next <= 63
                        const int b = mr >> 12;
                        const size_t widx =
                            ((((size_t)b << 6) + ((t >> 6) + 1)) * WARM +
                             (t & 15)) * D_DIM + d;
                        wtail[widx] = uval;
                    }
                }
            }
        }
    }
}

// ---------------------------------------------------------------------------
// Kernel 2: FUSED scan (R10 form: 1 d-chain/thread, unroll 8).
//   Warm-up u from gemm-written wtail (never overwritten; no in-place
//   hazard). a <= 0.5 => >=1 bit decay/step => 16-step warm-up error
//   <= 2^-16 |h|.
// ---------------------------------------------------------------------------
__global__ __launch_bounds__(256) void scan_fused(
    const unsigned short* __restrict__ a, const float* __restrict__ wtail,
    const float* __restrict__ h0, float* __restrict__ out)
{
    int tid = blockIdx.x * 256 + threadIdx.x;   // (b*NCHUNK + c)*1024 + d
    int d = tid & 1023;
    int bc = tid >> 10;
    int b = bc >> 6;
    int c = bc & (NCHUNK - 1);
    float h;
    if (c == 0) {
        h = h0[b * D_DIM + d];
    } else {
        h = 0.0f;
        size_t abase = ((size_t)b * T_DIM + (size_t)c * CHUNK_L - WARM) * D_DIM + d;
        size_t wbase = ((size_t)bc * WARM) * D_DIM + d;
        #pragma unroll 8
        for (int t = 0; t < WARM; t++) {
            float av = bfu(a[abase + (size_t)t * D_DIM]);
            float uv = wtail[wbase + (size_t)t * D_DIM];
            h = av * h + uv;
        }
    }
    size_t base = ((size_t)b * T_DIM + (size_t)c * CHUNK_L) * D_DIM + d;
    #pragma unroll 8
    for (int t = 0; t < CHUNK_L; t++) {
        size_t idx = base + (size_t)t * D_DIM;
        float av = bfu(a[idx]);
        float uv = out[idx];
        h = av * h + uv;
        out[idx] = h;
    }
    if (c == NCHUNK - 1)
        out[(size_t)M_DIM * D_DIM + b * D_DIM + d] = h;
}

// ---------------------------------------------------------------------------
extern "C" void kernel_launch(void* const* d_in, const int* in_sizes, int n_in,
                              void* d_out, int out_size, void* d_ws, size_t ws_size,
                              hipStream_t stream)
{
    const float* x  = (const float*)d_in[0];
    const float* h0 = (const float*)d_in[1];
    const float* Wr = (const float*)d_in[2];
    const float* br = (const float*)d_in[3];
    const float* Wi = (const float*)d_in[4];
    const float* bi = (const float*)d_in[5];
    const float* Wx = (const float*)d_in[6];
    float* out = (float*)d_out;

    char* ws = (char*)d_ws;
    unsigned short* xb = (unsigned short*)ws;                          // 32 MB
    unsigned short* wb = (unsigned short*)(ws + 33554432);             // 6 MB
    unsigned short* a_buf = (unsigned short*)(ws + 33554432 + 6291456);// 32 MB bf16
    float* wtail = (float*)(ws + 33554432 + 6291456 + 33554432);       // 16 MB

    // 0: fp32 -> bf16 (x and the three weights), grid-stride
    cvt_kernel<<<2048, 256, 0, stream>>>(x, Wr, Wi, Wx, xb, wb);
    // 1: 3-fused GEMM + gating (BK=64). a -> ws, u -> d_out, tails -> ws
    fused_gemm<<<1024, 512, 0, stream>>>(xb, wb, br, bi, a_buf, out, wtail);
    // 2: fused warm-up + in-place chunk scan + h_last
    scan_fused<<<1024, 256, 0, stream>>>(a_buf, wtail, h0, out);
}

// Round 12
// 281.701 us; speedup vs baseline: 1.0398x; 1.0398x over previous
//
#include <hip/hip_runtime.h>
#include <stdint.h>

#define D_DIM 1024
#define T_DIM 4096
#define B_DIM 4
#define M_DIM 16384
#define NX 16777216UL
#define NW 1048576UL
#define NTOT 19922944UL
#define LOG8F 2.0794415416798357f
#define CHUNK_L 64
#define NCHUNK 64
#define WARM 16
#define NT2 16

typedef __attribute__((ext_vector_type(4))) float f32x4;
typedef __attribute__((ext_vector_type(8))) short bf16x8;

__device__ __forceinline__ unsigned short f2bf(float f) {
    unsigned u = __float_as_uint(f);
    u += 0x7fffu + ((u >> 16) & 1u);
    return (unsigned short)(u >> 16);
}
__device__ __forceinline__ unsigned packbf2(float x, float y) {
    unsigned ux = __float_as_uint(x);
    ux = (ux + 0x7fffu + ((ux >> 16) & 1u)) >> 16;
    unsigned uy = __float_as_uint(y);
    uy = (uy + 0x7fffu + ((uy >> 16) & 1u)) & 0xffff0000u;
    return ux | uy;
}
__device__ __forceinline__ float bfu(unsigned short p) {
    return __uint_as_float((unsigned)p << 16);
}
__device__ __forceinline__ float sigm(float x) { return 1.0f / (1.0f + __expf(-x)); }

__device__ __forceinline__ void gl_lds16(const void* g, void* l) {
    __builtin_amdgcn_global_load_lds(
        (const __attribute__((address_space(1))) void*)g,
        (__attribute__((address_space(3))) void*)l, 16, 0, 0);
}

// ---------------------------------------------------------------------------
// Kernel 0: convert x, W_r, W_i, W_x  fp32 -> bf16 (R10 grid-stride form).
// ---------------------------------------------------------------------------
__global__ __launch_bounds__(256) void cvt_kernel(
    const float* __restrict__ x, const float* __restrict__ Wr,
    const float* __restrict__ Wi, const float* __restrict__ Wx,
    unsigned short* __restrict__ xb, unsigned short* __restrict__ wb)
{
    const size_t stride = (size_t)gridDim.x * 256 * 8;
    for (size_t i = ((size_t)blockIdx.x * 256 + threadIdx.x) * 8;
         i < NTOT; i += stride) {
        const float* src;
        unsigned short* dst;
        size_t off;
        if (i < NX) {
            src = x; dst = xb; off = i;
        } else {
            size_t j = i - NX;
            size_t w = j >> 20;           // / NW
            off = j & (NW - 1);
            src = (w == 0) ? Wr : (w == 1 ? Wi : Wx);
            dst = wb + w * NW;
        }
        float4 v0 = *(const float4*)(src + off);
        float4 v1 = *(const float4*)(src + off + 4);
        uint4 o;
        o.x = packbf2(v0.x, v0.y);
        o.y = packbf2(v0.z, v0.w);
        o.z = packbf2(v1.x, v1.y);
        o.w = packbf2(v1.z, v1.w);
        *(uint4*)(dst + off) = o;
    }
}

// ---------------------------------------------------------------------------
// Kernel 1: 3-fused GEMM + gating. R12: BK=64 ping-pong, NO setprio,
//   half-tile read/MFMA interleave.
//   R11 diagnosis: per 64-K tile = 5197 cy ~= SERIAL sum of LDS pipe
//   (160 ds_read x 12cy + gl_lds writes ~ 2700cy) and matrix pipe (384
//   MFMA x 4.85 ~ 1862cy) + sync. Three schedule families (reg-dbuf,
//   4-deep, ping-pong) all ~140us -> pipes never overlap. Suspected
//   serializer (present since R0): s_setprio(1) around the MFMA cluster
//   in a barrier-LOCKSTEP kernel -- waves entering MFMAs at prio 1 starve
//   the issue slots of waves still issuing their prio-0 ds_reads, so the
//   read phase and MFMA phase serialize CU-wide (m190 measured setprio
//   HURTS lockstep GEMM). A/B this round: setprio REMOVED; additionally
//   half-1's 10 ds_reads are software-interleaved between half-0's MFMA
//   groups so read-issue is spread through the MFMA burst.
//   - 2-deep ping-pong (2 x 64 KB), vmcnt(0)+barrier once per tile (own
//     stage(t) was issued a full tile ago -> near-free drain; drain-before-
//     barrier publishes our gl_lds writes to the other waves).
//   - race audit unchanged from R11 (passed): stage(t+1) writes the buffer
//     whose tile-(t-1) readers all drained before the tile-t barrier.
//   - 8-group XOR swizzle (cg ^= row&7), 0 conflicts measured.
//   - regs: acc 96 (AGPR) + frags 80 + addr -> VGPR_Count ~112, no spill.
//   - bid&7 = d-tile = XCD keeps per-XCD W-slice L2-resident (proven).
//   - R8: B direct-to-reg 1.9x worse. R4: bigger wave tiles spill.
//   Epilogue: gating + wtail chunk-tail copy (unchanged, verified).
// ---------------------------------------------------------------------------
__global__ __launch_bounds__(512, 2) void fused_gemm(
    const unsigned short* __restrict__ xb, const unsigned short* __restrict__ wb,
    const float* __restrict__ b_r, const float* __restrict__ b_i,
    unsigned short* __restrict__ a_out, float* __restrict__ u_out,
    float* __restrict__ wtail)
{
    // per buffer (32768 ush = 64 KB): A[128][64] then B[3][128][64]
    __shared__ __align__(16) unsigned short lds[2][32768];   // 128 KB

    const int tid  = threadIdx.x;
    const int lane = tid & 63;
    const int wave = tid >> 6;
    const int wm = wave & 1;            // m-half (64 rows of 128)
    const int wn = wave >> 1;           // d-quarter (32 cols of 128)
    const int m0 = ((int)blockIdx.x >> 3) * 128;
    const int d0 = ((int)blockIdx.x & 7) * 128;
    const int frow = lane & 15;
    const int kgrp = lane >> 4;

    // staging: rows tid/8 (+64), col-group tid&7 of 8; source col-group
    // inverse-swizzled (cgs = c ^ (row&7)); (row+64)&7 == row&7.
    const int r_0 = tid >> 3;           // 0..63
    const int c_0 = tid & 7;
    const int cgs = c_0 ^ (r_0 & 7);
    const unsigned short* srcA = xb + (size_t)(m0 + r_0) * D_DIM + cgs * 8;
    const unsigned short* srcB = wb + (size_t)(d0 + r_0) * D_DIM + cgs * 8;

    // reader offsets (ushort units), swizzle folded in; ks = K-half (0,1)
    int offA[4][2], offB[3][2][2];
    #pragma unroll
    for (int i = 0; i < 4; i++) {
        const int row = wm * 64 + i * 16 + frow;
        #pragma unroll
        for (int ks = 0; ks < 2; ks++)
            offA[i][ks] = row * 64 + ((((ks * 4) + kgrp) ^ (row & 7)) << 3);
    }
    #pragma unroll
    for (int w = 0; w < 3; w++)
        #pragma unroll
        for (int j = 0; j < 2; j++) {
            const int row = wn * 32 + j * 16 + frow;
            #pragma unroll
            for (int ks = 0; ks < 2; ks++)
                offB[w][j][ks] = 8192 + w * 8192 + row * 64 +
                                 ((((ks * 4) + kgrp) ^ (row & 7)) << 3);
        }

    f32x4 acc[3][4][2];
    #pragma unroll
    for (int w = 0; w < 3; w++)
        #pragma unroll
        for (int i = 0; i < 4; i++)
            #pragma unroll
            for (int j = 0; j < 2; j++) acc[w][i][j] = (f32x4){0.f, 0.f, 0.f, 0.f};

    auto stage = [&](int t) {           // 8 gl_lds per thread per 64-K tile
        unsigned short* L = &lds[t & 1][0];
        const int k0 = t << 6;
        gl_lds16(srcA + k0,                &L[tid * 8]);
        gl_lds16(srcA + 64 * D_DIM + k0,   &L[4096 + tid * 8]);
        #pragma unroll
        for (int w = 0; w < 3; w++) {
            const unsigned short* bw = srcB + (size_t)w * NW + k0;
            gl_lds16(bw,                &L[8192 + w * 8192 + tid * 8]);
            gl_lds16(bw + 64 * D_DIM,   &L[8192 + w * 8192 + 4096 + tid * 8]);
        }
    };

    stage(0);

#define MF0(w, i, j) \
    acc[w][i][j] = __builtin_amdgcn_mfma_f32_16x16x32_bf16( \
        af0[i], bf0[w][j], acc[w][i][j], 0, 0, 0)
#define MF1(w, i, j) \
    acc[w][i][j] = __builtin_amdgcn_mfma_f32_16x16x32_bf16( \
        af1[i], bf1[w][j], acc[w][i][j], 0, 0, 0)

    for (int t = 0; t < NT2; ++t) {
        // own stage(t) issued a full tile ago -> near-free drain; also
        // publishes our gl_lds writes before the barrier.
        asm volatile("s_waitcnt vmcnt(0)" ::: "memory");
        __builtin_amdgcn_s_barrier();
        asm volatile("" ::: "memory");

        const unsigned short* Lb = &lds[t & 1][0];
        bf16x8 af0[4], bf0[3][2], af1[4], bf1[3][2];

        // half-0 fragment reads
        #pragma unroll
        for (int i = 0; i < 4; i++) af0[i] = *(const bf16x8*)&Lb[offA[i][0]];
        #pragma unroll
        for (int w = 0; w < 3; w++)
            #pragma unroll
            for (int j = 0; j < 2; j++)
                bf0[w][j] = *(const bf16x8*)&Lb[offB[w][j][0]];

        if (t + 1 < NT2) stage(t + 1);   // vmem issue early, under compute

        // half-0 MFMAs with half-1 reads spread between groups
        MF0(0,0,0); MF0(0,0,1); MF0(0,1,0); MF0(0,1,1);
        af1[0] = *(const bf16x8*)&Lb[offA[0][1]];
        af1[1] = *(const bf16x8*)&Lb[offA[1][1]];
        MF0(0,2,0); MF0(0,2,1); MF0(0,3,0); MF0(0,3,1);
        af1[2] = *(const bf16x8*)&Lb[offA[2][1]];
        af1[3] = *(const bf16x8*)&Lb[offA[3][1]];
        MF0(1,0,0); MF0(1,0,1); MF0(1,1,0); MF0(1,1,1);
        bf1[0][0] = *(const bf16x8*)&Lb[offB[0][0][1]];
        bf1[0][1] = *(const bf16x8*)&Lb[offB[0][1][1]];
        MF0(1,2,0); MF0(1,2,1); MF0(1,3,0); MF0(1,3,1);
        bf1[1][0] = *(const bf16x8*)&Lb[offB[1][0][1]];
        bf1[1][1] = *(const bf16x8*)&Lb[offB[1][1][1]];
        MF0(2,0,0); MF0(2,0,1); MF0(2,1,0); MF0(2,1,1);
        bf1[2][0] = *(const bf16x8*)&Lb[offB[2][0][1]];
        bf1[2][1] = *(const bf16x8*)&Lb[offB[2][1][1]];
        MF0(2,2,0); MF0(2,2,1); MF0(2,3,0); MF0(2,3,1);

        // half-1 MFMAs
        #pragma unroll
        for (int w = 0; w < 3; w++)
            #pragma unroll
            for (int i = 0; i < 4; i++) {
                MF1(w,i,0); MF1(w,i,1);
            }
    }
#undef MF0
#undef MF1

    // Epilogue. C/D layout: col(d) = lane&15, row(m) = (lane>>4)*4 + r.
    const int mb = m0 + wm * 64 + kgrp * 4;
    const int db = d0 + wn * 32 + frow;
    #pragma unroll
    for (int j = 0; j < 2; j++) {
        const int d = db + j * 16;
        const float br = b_r[d];
        const float bi = b_i[d];
        #pragma unroll
        for (int i = 0; i < 4; i++) {
            const int m = mb + i * 16;
            #pragma unroll
            for (int r = 0; r < 4; r++) {
                const int mr = m + r;
                const size_t idx = (size_t)mr * D_DIM + d;
                float rg = sigm(acc[0][i][j][r] + br);
                // exp(-softplus(z)) == sigmoid(-z);  a in (0.11, 0.5)
                float a = sigm(-LOG8F * rg);
                a_out[idx] = f2bf(a);
                float g = sqrtf(fmaxf(1.0f - a * a, 1e-6f));
                float uval = g * sigm(acc[1][i][j][r] + bi) * acc[2][i][j][r];
                u_out[idx] = uval;
                // chunk-tail copy for the fused scan's warm-up.
                if (i == 3) {
                    const int t = mr & 4095;
                    if (t < 4032) {     // c_next <= 63
                        const int b = mr >> 12;
                        const size_t widx =
                            ((((size_t)b << 6) + ((t >> 6) + 1)) * WARM +
                             (t & 15)) * D_DIM + d;
                        wtail[widx] = uval;
                    }
                }
            }
        }
    }
}

// ---------------------------------------------------------------------------
// Kernel 2: FUSED scan (R10 form: 1 d-chain/thread, unroll 8).
//   Warm-up u from gemm-written wtail (never overwritten; no in-place
//   hazard). a <= 0.5 => >=1 bit decay/step => 16-step warm-up error
//   <= 2^-16 |h|.
// ---------------------------------------------------------------------------
__global__ __launch_bounds__(256) void scan_fused(
    const unsigned short* __restrict__ a, const float* __restrict__ wtail,
    const float* __restrict__ h0, float* __restrict__ out)
{
    int tid = blockIdx.x * 256 + threadIdx.x;   // (b*NCHUNK + c)*1024 + d
    int d = tid & 1023;
    int bc = tid >> 10;
    int b = bc >> 6;
    int c = bc & (NCHUNK - 1);
    float h;
    if (c == 0) {
        h = h0[b * D_DIM + d];
    } else {
        h = 0.0f;
        size_t abase = ((size_t)b * T_DIM + (size_t)c * CHUNK_L - WARM) * D_DIM + d;
        size_t wbase = ((size_t)bc * WARM) * D_DIM + d;
        #pragma unroll 8
        for (int t = 0; t < WARM; t++) {
            float av = bfu(a[abase + (size_t)t * D_DIM]);
            float uv = wtail[wbase + (size_t)t * D_DIM];
            h = av * h + uv;
        }
    }
    size_t base = ((size_t)b * T_DIM + (size_t)c * CHUNK_L) * D_DIM + d;
    #pragma unroll 8
    for (int t = 0; t < CHUNK_L; t++) {
        size_t idx = base + (size_t)t * D_DIM;
        float av = bfu(a[idx]);
        float uv = out[idx];
        h = av * h + uv;
        out[idx] = h;
    }
    if (c == NCHUNK - 1)
        out[(size_t)M_DIM * D_DIM + b * D_DIM + d] = h;
}

// ---------------------------------------------------------------------------
extern "C" void kernel_launch(void* const* d_in, const int* in_sizes, int n_in,
                              void* d_out, int out_size, void* d_ws, size_t ws_size,
                              hipStream_t stream)
{
    const float* x  = (const float*)d_in[0];
    const float* h0 = (const float*)d_in[1];
    const float* Wr = (const float*)d_in[2];
    const float* br = (const float*)d_in[3];
    const float* Wi = (const float*)d_in[4];
    const float* bi = (const float*)d_in[5];
    const float* Wx = (const float*)d_in[6];
    float* out = (float*)d_out;

    char* ws = (char*)d_ws;
    unsigned short* xb = (unsigned short*)ws;                          // 32 MB
    unsigned short* wb = (unsigned short*)(ws + 33554432);             // 6 MB
    unsigned short* a_buf = (unsigned short*)(ws + 33554432 + 6291456);// 32 MB bf16
    float* wtail = (float*)(ws + 33554432 + 6291456 + 33554432);       // 16 MB

    // 0: fp32 -> bf16 (x and the three weights), grid-stride
    cvt_kernel<<<2048, 256, 0, stream>>>(x, Wr, Wi, Wx, xb, wb);
    // 1: 3-fused GEMM + gating (BK=64, no setprio, interleaved halves)
    fused_gemm<<<1024, 512, 0, stream>>>(xb, wb, br, bi, a_buf, out, wtail);
    // 2: fused warm-up + in-place chunk scan + h_last
    scan_fused<<<1024, 256, 0, stream>>>(a_buf, wtail, h0, out);
}